// Round 2
// baseline (3316.055 us; speedup 1.0000x reference)
//
#include <hip/hip_runtime.h>
#include <hip/hip_fp16.h>

// RaBitQ forward. x: 262144 vectors of D=128 fp32. P: 128x128 orthonormal fp32.
// out f32 concat: x_hat[262144*128] | packed[262144*16] | norms16[262144] | x016[262144]
//
// Block = 256 (4 waves = 2 pairs). Pair handles 16 vectors/pass, PASSES=4 -> 128 vec/block.
// Wave "half" h owns rotated coords / output cols e,f in [64h, 64h+64).
// Quantize: P row e register-resident (128 VGPR), x wave-uniform float4 loads,
//           per-element fmaf chain in ascending d (BIT-IDENTICAL to round-1 kernel).
// Dequant:  x_hat = (n16*x016) * (S @ P), S=+-1 bf16 exact, P as bf16 hi+lo fragments
//           cached in registers; mfma_f32_16x16x32_bf16, M=16 vecs, K=128, N=64 per wave.
// LDS: 2 KiB (mask + partial exchange, parity double-buffered) -> occupancy reg-bound.

#define NVEC_TOTAL (4 * 16 * 4096)
#define PASSES 4

typedef short short8 __attribute__((ext_vector_type(8)));
typedef float f32x4 __attribute__((ext_vector_type(4)));
typedef unsigned int u32x4v __attribute__((ext_vector_type(4)));
typedef unsigned long long ull;

__device__ __forceinline__ ull sel16_u64(const ull* a, int s) {
  ull b0 = (s & 1) ? a[1] : a[0],  b1 = (s & 1) ? a[3] : a[2];
  ull b2 = (s & 1) ? a[5] : a[4],  b3 = (s & 1) ? a[7] : a[6];
  ull b4 = (s & 1) ? a[9] : a[8],  b5 = (s & 1) ? a[11] : a[10];
  ull b6 = (s & 1) ? a[13] : a[12], b7 = (s & 1) ? a[15] : a[14];
  ull c0 = (s & 2) ? b1 : b0, c1 = (s & 2) ? b3 : b2;
  ull c2 = (s & 2) ? b5 : b4, c3 = (s & 2) ? b7 : b6;
  ull d0 = (s & 4) ? c1 : c0, d1 = (s & 4) ? c3 : c2;
  return (s & 8) ? d1 : d0;
}

__device__ __forceinline__ float sel16_f(const float* a, int s) {
  float b0 = (s & 1) ? a[1] : a[0],  b1 = (s & 1) ? a[3] : a[2];
  float b2 = (s & 1) ? a[5] : a[4],  b3 = (s & 1) ? a[7] : a[6];
  float b4 = (s & 1) ? a[9] : a[8],  b5 = (s & 1) ? a[11] : a[10];
  float b6 = (s & 1) ? a[13] : a[12], b7 = (s & 1) ? a[15] : a[14];
  float c0 = (s & 2) ? b1 : b0, c1 = (s & 2) ? b3 : b2;
  float c2 = (s & 2) ? b5 : b4, c3 = (s & 2) ? b7 : b6;
  float d0 = (s & 4) ? c1 : c0, d1 = (s & 4) ? c3 : c2;
  return (s & 8) ? d1 : d0;
}

__global__ __launch_bounds__(256, 4) void rabitq_fwd(const float* __restrict__ x,
                                                     const float* __restrict__ Pm,
                                                     float* __restrict__ out) {
  __shared__ float red[2][2][16][4];            // [parity][pair][vec][s1a,n2a,s1b,n2b]
  __shared__ unsigned char msk[2][2][16][16];   // [parity][pair][vec][byte 0..15]

  const int tid = threadIdx.x, lane = tid & 63, ww = tid >> 6;
  const int pair = ww >> 1, half = ww & 1;
  const int l15 = lane & 15, lg = lane >> 4;

  float* const out_xhat = out;
  float* const out_pack = out + (size_t)NVEC_TOTAL * 128;
  float* const out_norm = out_pack + (size_t)NVEC_TOTAL * 16;
  float* const out_x0   = out_norm + NVEC_TOTAL;

  // ---- one-time: register-resident P row e (for quantize) ----
  const int e = half * 64 + lane;
  float4 pr[32];
  {
    const float4* pre = (const float4*)(Pm + (size_t)e * 128);
#pragma unroll
    for (int j = 0; j < 32; ++j) pr[j] = pre[j];
  }

  // ---- one-time: dequant B fragments, bf16 hi/lo, register-cached ----
  // B[k][n]: k = ks*32 + lg*8 + i, col f = half*64 + n*16 + l15, element P[k][f].
  short8 bhi[4][4], blo[4][4];
#pragma unroll
  for (int n = 0; n < 4; ++n) {
#pragma unroll
    for (int ks = 0; ks < 4; ++ks) {
      const int f = half * 64 + n * 16 + l15;
      const int kb = ks * 32 + lg * 8;
      unsigned int hw[4], lw[4];
#pragma unroll
      for (int j = 0; j < 4; ++j) {
        const float p0 = Pm[(size_t)(kb + 2 * j) * 128 + f];
        const float p1 = Pm[(size_t)(kb + 2 * j + 1) * 128 + f];
        const unsigned int u0 = __float_as_uint(p0), u1 = __float_as_uint(p1);
        hw[j] = (u0 >> 16) | (u1 & 0xFFFF0000u);
        const float l0 = p0 - __uint_as_float(u0 & 0xFFFF0000u);  // exact
        const float l1 = p1 - __uint_as_float(u1 & 0xFFFF0000u);  // exact
        lw[j] = (__float_as_uint(l0) >> 16) | (__float_as_uint(l1) & 0xFFFF0000u);
      }
      u32x4v th, tl;
      th[0] = hw[0]; th[1] = hw[1]; th[2] = hw[2]; th[3] = hw[3];
      tl[0] = lw[0]; tl[1] = lw[1]; tl[2] = lw[2]; tl[3] = lw[3];
      bhi[n][ks] = __builtin_bit_cast(short8, th);
      blo[n][ks] = __builtin_bit_cast(short8, tl);
    }
  }

  const int gp = blockIdx.x * 2 + pair;  // global pair id

#pragma unroll 1
  for (int t = 0; t < PASSES; ++t) {
    const int vbase = gp * (PASSES * 16) + t * 16;
    const int par = t & 1;

    // ================= quantize: acc[v] = sum_d x[v][d] * P[e][d] =================
    float acc[16];
#pragma unroll
    for (int v = 0; v < 16; ++v) acc[v] = 0.f;
#pragma unroll
    for (int v = 0; v < 16; ++v) {
      const float4* xv = (const float4*)(x + (size_t)(vbase + v) * 128);
      float a = acc[v];
#pragma unroll
      for (int b = 0; b < 4; ++b) {
        float4 q[8];
#pragma unroll
        for (int j = 0; j < 8; ++j) q[j] = xv[b * 8 + j];
#pragma unroll
        for (int j = 0; j < 8; ++j) {
          a = fmaf(q[j].x, pr[b * 8 + j].x, a);
          a = fmaf(q[j].y, pr[b * 8 + j].y, a);
          a = fmaf(q[j].z, pr[b * 8 + j].z, a);
          a = fmaf(q[j].w, pr[b * 8 + j].w, a);
        }
      }
      acc[v] = a;
    }

    // ---- signs (ballot) + per-vec reductions over this wave's 64 coords ----
    ull bm[16];
    float s1v[16], n2v[16];
#pragma unroll
    for (int v = 0; v < 16; ++v) {
      bm[v] = __ballot(acc[v] >= 0.0f);
      const float aa = fabsf(acc[v]);
      float s1 = aa, n2 = aa * aa;
#pragma unroll
      for (int off = 32; off; off >>= 1) {
        s1 += __shfl_xor(s1, off);
        n2 += __shfl_xor(n2, off);
      }
      s1v[v] = s1; n2v[v] = n2;
    }

    // ---- exchange: masks + partial (s1,n2) via LDS ----
    {
      const ull m = sel16_u64(bm, l15);
      const float ws1 = sel16_f(s1v, l15);
      const float wn2 = sel16_f(n2v, l15);
      if (lane < 16) {
        *(ull*)&msk[par][pair][l15][8 * half] = m;
        float2 p2; p2.x = ws1; p2.y = wn2;
        *(float2*)&red[par][pair][l15][2 * half] = p2;
      }
    }
    __syncthreads();

    // ---- finalize norm / x0 (vec = l15) ----
    const float4 rr = *(const float4*)&red[par][pair][l15][0];
    const float s1 = rr.x + rr.z, n2 = rr.y + rr.w;
    const float norm = fmaxf(sqrtf(n2), 1e-8f);
    const float n16 = __half2float(__float2half(norm));
    const float x0 = s1 / (128.0f * norm);
    const float x016 = __half2float(__float2half(x0));
    if (half == 0 && lane < 16) {
      out_norm[vbase + l15] = n16;
      out_x0[vbase + l15] = x016;
    }
    const float scale = n16 * x016;
    float sc[4];
#pragma unroll
    for (int r = 0; r < 4; ++r)
      sc[r] = __int_as_float(__builtin_amdgcn_ds_bpermute((lg * 4 + r) << 2,
                                                          __float_as_int(scale)));

    // ---- packed bytes (this wave's half: bytes 8*half .. 8*half+7) ----
#pragma unroll
    for (int k = 0; k < 2; ++k) {
      const int i = lane + 64 * k;
      const int vec = i >> 3, byte = i & 7;
      const float val = (float)msk[par][pair][vec][8 * half + byte];
      out_pack[(size_t)(vbase + vec) * 16 + 8 * half + byte] = val;
    }

    // ================= dequantize: D = S @ (P_hi + P_lo), MFMA =================
    f32x4 dacc[4];
#pragma unroll
    for (int n = 0; n < 4; ++n) { dacc[n][0] = 0.f; dacc[n][1] = 0.f; dacc[n][2] = 0.f; dacc[n][3] = 0.f; }
#pragma unroll
    for (int ks = 0; ks < 4; ++ks) {
      const unsigned int b = msk[par][pair][l15][ks * 4 + lg];  // A row=l15, k-group=lg
      const unsigned int nb = ~b;  // bit=1 -> +1 (sign bit clear), bit=0 -> -1
      u32x4v ta;
      ta[0] = 0x3F803F80u | ((nb & 1u) << 15)          | ((nb & 2u) << 30);
      ta[1] = 0x3F803F80u | (((nb >> 2) & 1u) << 15)   | (((nb >> 2) & 2u) << 30);
      ta[2] = 0x3F803F80u | (((nb >> 4) & 1u) << 15)   | (((nb >> 4) & 2u) << 30);
      ta[3] = 0x3F803F80u | (((nb >> 6) & 1u) << 15)   | (((nb >> 6) & 2u) << 30);
      const short8 a8 = __builtin_bit_cast(short8, ta);
#pragma unroll
      for (int n = 0; n < 4; ++n) {
        dacc[n] = __builtin_amdgcn_mfma_f32_16x16x32_bf16(a8, bhi[n][ks], dacc[n], 0, 0, 0);
        dacc[n] = __builtin_amdgcn_mfma_f32_16x16x32_bf16(a8, blo[n][ks], dacc[n], 0, 0, 0);
      }
    }

    // C/D layout (verified): col = lane&15, row = (lane>>4)*4 + reg
#pragma unroll
    for (int n = 0; n < 4; ++n) {
#pragma unroll
      for (int r = 0; r < 4; ++r) {
        const int row = lg * 4 + r;
        const int f = half * 64 + n * 16 + l15;
        out_xhat[(size_t)(vbase + row) * 128 + f] = sc[r] * dacc[n][r];
      }
    }
  }
}

extern "C" void kernel_launch(void* const* d_in, const int* in_sizes, int n_in,
                              void* d_out, int out_size, void* d_ws, size_t ws_size,
                              hipStream_t stream) {
  const float* x  = (const float*)d_in[0];
  const float* Pm = (const float*)d_in[1];
  float* out = (float*)d_out;
  // 262144 vectors / (2 pairs * 4 passes * 16 vec) = 2048 blocks, exact cover.
  hipLaunchKernelGGL(rabitq_fwd, dim3(2048), dim3(256), 0, stream, x, Pm, out);
}

// Round 5
// 423.517 us; speedup vs baseline: 7.8298x; 7.8298x over previous
//
#include <hip/hip_runtime.h>
#include <hip/hip_fp16.h>

// RaBitQ forward, split into two proven kernels.
// x: 262144 vectors of D=128 fp32. P: 128x128 fp32 orthonormal.
// out f32 concat: x_hat[262144*128] | packed[262144*16] | norms16[262144] | x016[262144]
//
// Kernel A (quantize): round-1 kernel's quantize/ballot/pack code VERBATIM
//   (that exact fmaf chain passed vs np). Block 512 = 8 waves sharing the
//   64 KiB swizzled fp32 P -> 2 blocks/CU = 4 waves/SIMD (2x round-1 occ).
//   Writes packed bytes, norms16, x016.
// Kernel B (dequant): round-2's PROVEN MFMA path (A-frag sign construction,
//   B-frag indexing, C/D layout all passed on HW). B = bf16(P) prepacked in
//   32 KiB LDS; A-masks rebuilt from out_pack bytes (the verified output);
//   scale = out_norm * out_x0. x_hat = scale * (S @ bf16(P)).
//   bf16 P rounding -> x_hat err ~2e-3 << 0.0625 margin that passed in R1.

#define NVEC_TOTAL (4 * 16 * 4096)

typedef short short8 __attribute__((ext_vector_type(8)));
typedef float f32x4 __attribute__((ext_vector_type(4)));
typedef unsigned int u32x4v __attribute__((ext_vector_type(4)));
typedef unsigned long long ull;

__device__ __forceinline__ float rfl_f(float v) {
  return __int_as_float(__builtin_amdgcn_readfirstlane(__float_as_int(v)));
}

__device__ __forceinline__ ull sel8_u64(const ull* a, int s) {
  ull r0 = (s & 1) ? a[1] : a[0];
  ull r1 = (s & 1) ? a[3] : a[2];
  ull r2 = (s & 1) ? a[5] : a[4];
  ull r3 = (s & 1) ? a[7] : a[6];
  ull r4 = (s & 2) ? r1 : r0;
  ull r5 = (s & 2) ? r3 : r2;
  return (s & 4) ? r5 : r4;
}

__device__ __forceinline__ float sel8_f(const float* a, int s) {
  float r0 = (s & 1) ? a[1] : a[0];
  float r1 = (s & 1) ? a[3] : a[2];
  float r2 = (s & 1) ? a[5] : a[4];
  float r3 = (s & 1) ? a[7] : a[6];
  float r4 = (s & 2) ? r1 : r0;
  float r5 = (s & 2) ? r3 : r2;
  return (s & 4) ? r5 : r4;
}

__device__ __forceinline__ unsigned short f2bf(float f) {  // fp32 -> bf16 RNE
  unsigned u = __float_as_uint(f);
  return (unsigned short)((u + 0x7FFFu + ((u >> 16) & 1u)) >> 16);
}

// ========================= Kernel A: quantize =========================
__global__ __launch_bounds__(512, 4) void rabitq_quant(const float* __restrict__ x,
                                                       const float* __restrict__ Pm,
                                                       float* __restrict__ out) {
  __shared__ __align__(16) float Pl[128 * 128];  // 64 KiB, swizzled as round-1

  const int tid = threadIdx.x;
  const int lane = tid & 63;

  // stage P into LDS, swizzled (16B blocks, j ^ (row&7)) — 512-thread version
  {
    const int r = tid >> 2;        // row 0..127, four threads per row
    const int q = tid & 3;
#pragma unroll
    for (int c = 0; c < 8; ++c) {
      const int dd = q * 32 + c * 4;
      const int sj = (((dd >> 2) ^ (r & 7)) << 2);
      const float4 v = *(const float4*)(Pm + (size_t)r * 128 + dd);
      *(float4*)(&Pl[r * 128 + sj]) = v;
    }
  }
  __syncthreads();

  const int w = blockIdx.x * 8 + (tid >> 6);  // global wave id, 0..8191
  float* const out_pack = out + (size_t)NVEC_TOTAL * 128;
  float* const out_norm = out_pack + (size_t)NVEC_TOTAL * 16;
  float* const out_x0   = out_norm + NVEC_TOTAL;

  const int sw1 = lane & 7;  // row-swizzle key (same for lane and lane+64)

  for (int t = 0; t < 4; ++t) {
    const int vbase = w * 32 + t * 8;
    const float* const xb = x + (size_t)vbase * 128;

    // ---- x_rot = x @ P^T : VERBATIM round-1 chain (signs proven vs np) ----
    float acc_lo[8], acc_hi[8];
#pragma unroll
    for (int v = 0; v < 8; ++v) { acc_lo[v] = 0.f; acc_hi[v] = 0.f; }

#pragma unroll 2
    for (int j = 0; j < 32; ++j) {
      const int js = ((j ^ sw1) << 2);
      const float4 pl = *(const float4*)(&Pl[lane * 128 + js]);
      const float4 ph = *(const float4*)(&Pl[(lane + 64) * 128 + js]);
#pragma unroll
      for (int v = 0; v < 8; ++v) {
        const float4 xv = *(const float4*)(xb + v * 128 + j * 4);
        float al = acc_lo[v], ah = acc_hi[v];
        al = fmaf(xv.x, pl.x, al); ah = fmaf(xv.x, ph.x, ah);
        al = fmaf(xv.y, pl.y, al); ah = fmaf(xv.y, ph.y, ah);
        al = fmaf(xv.z, pl.z, al); ah = fmaf(xv.z, ph.z, ah);
        al = fmaf(xv.w, pl.w, al); ah = fmaf(xv.w, ph.w, ah);
        acc_lo[v] = al; acc_hi[v] = ah;
      }
    }

    // ---- signs, norm, x0 : VERBATIM round-1 ----
    ull bl[8], bh[8];
    float n16v[8], x0v[8];
#pragma unroll
    for (int v = 0; v < 8; ++v) {
      bl[v] = __ballot(acc_lo[v] >= 0.0f);
      bh[v] = __ballot(acc_hi[v] >= 0.0f);
      const float a1 = fabsf(acc_lo[v]);
      const float a2 = fabsf(acc_hi[v]);
      float s1 = a1 + a2;
      float n2 = fmaf(a1, a1, a2 * a2);
#pragma unroll
      for (int off = 32; off > 0; off >>= 1) {
        s1 += __shfl_xor(s1, off);
        n2 += __shfl_xor(n2, off);
      }
      float norm = fmaxf(sqrtf(n2), 1e-8f);
      const float n16  = __half2float(__float2half(norm));
      const float x0   = s1 / (128.0f * norm);
      const float x016 = __half2float(__float2half(x0));
      n16v[v] = rfl_f(n16);
      x0v[v]  = rfl_f(x016);
    }

    // ---- store packed bytes / norms16 / x016 : VERBATIM round-1 ----
    {
      const int s = lane & 7;
      const int jb = lane >> 3;
      const ull el = sel8_u64(bl, s);
      const ull eh = sel8_u64(bh, s);
      const float fl = (float)((unsigned)(el >> (8 * jb)) & 255u);
      const float fh = (float)((unsigned)(eh >> (8 * jb)) & 255u);
      out_pack[(size_t)(vbase + s) * 16 + jb] = fl;
      out_pack[(size_t)(vbase + s) * 16 + 8 + jb] = fh;
      if (lane < 16) {
        const float nsel = sel8_f(n16v, s);
        const float xsel = sel8_f(x0v, s);
        if (lane < 8) out_norm[vbase + s] = nsel;
        else          out_x0[vbase + s] = xsel;
      }
    }
  }
}

// ========================= Kernel B: dequantize =========================
__global__ __launch_bounds__(256, 4) void rabitq_dequant(const float* __restrict__ Pm,
                                                         float* __restrict__ out) {
  __shared__ __align__(16) unsigned Bp[2048 * 4];  // 32 KiB bf16 B-frags

  const int tid = threadIdx.x, lane = tid & 63, ww = tid >> 6;
  const int l15 = lane & 15, lg = lane >> 4;

  // build Bp from global P: slot s=(ks*512+n*64+l) holds B-frag regs for
  // (ks,n,lane=l): elem j -> k=ks*32+(l>>4)*8+j, col f=n*16+(l&15).
  // Same element indexing as round-2's PASSING register build.
#pragma unroll
  for (int i = 0; i < 8; ++i) {
    const int s = tid + i * 256;
    const int ks = s >> 9, n = (s >> 6) & 7, l = s & 63;
    const int kb = ks * 32 + (l >> 4) * 8;
    const int f = n * 16 + (l & 15);
    u32x4v wv;
#pragma unroll
    for (int u = 0; u < 4; ++u) {
      const float p0 = Pm[(size_t)(kb + 2 * u) * 128 + f];
      const float p1 = Pm[(size_t)(kb + 2 * u + 1) * 128 + f];
      wv[u] = (unsigned)f2bf(p0) | ((unsigned)f2bf(p1) << 16);
    }
    *(u32x4v*)(&Bp[s * 4]) = wv;
  }
  __syncthreads();

  const float* const out_pack = out + (size_t)NVEC_TOTAL * 128;
  const float* const out_norm = out_pack + (size_t)NVEC_TOTAL * 16;
  const float* const out_x0   = out_norm + NVEC_TOTAL;

#pragma unroll 1
  for (int t = 0; t < 4; ++t) {
    const int vbase = (blockIdx.x * 4 + ww) * 64 + t * 16;
    const int vec = vbase + l15;

    // ---- masks from the packed bytes kernel A wrote (verified data path) ----
    const float* pb = out_pack + (size_t)vec * 16;
    const float4 b0 = *(const float4*)(pb + 0);
    const float4 b1 = *(const float4*)(pb + 4);
    const float4 b2 = *(const float4*)(pb + 8);
    const float4 b3 = *(const float4*)(pb + 12);
    unsigned mw[4];
    mw[0] = (unsigned)b0.x | ((unsigned)b0.y << 8) | ((unsigned)b0.z << 16) | ((unsigned)b0.w << 24);
    mw[1] = (unsigned)b1.x | ((unsigned)b1.y << 8) | ((unsigned)b1.z << 16) | ((unsigned)b1.w << 24);
    mw[2] = (unsigned)b2.x | ((unsigned)b2.y << 8) | ((unsigned)b2.z << 16) | ((unsigned)b2.w << 24);
    mw[3] = (unsigned)b3.x | ((unsigned)b3.y << 8) | ((unsigned)b3.z << 16) | ((unsigned)b3.w << 24);

    // ---- A-frags: round-2's PASSING sign construction ----
    short8 a8[4];
#pragma unroll
    for (int ks = 0; ks < 4; ++ks) {
      const unsigned nb = (~mw[ks]) >> (lg * 8);
      u32x4v ta;
      ta[0] = 0x3F803F80u | ((nb & 1u) << 15)        | ((nb & 2u) << 30);
      ta[1] = 0x3F803F80u | (((nb >> 2) & 1u) << 15) | (((nb >> 2) & 2u) << 30);
      ta[2] = 0x3F803F80u | (((nb >> 4) & 1u) << 15) | (((nb >> 4) & 2u) << 30);
      ta[3] = 0x3F803F80u | (((nb >> 6) & 1u) << 15) | (((nb >> 6) & 2u) << 30);
      a8[ks] = __builtin_bit_cast(short8, ta);
    }

    // ---- D = S @ bf16(P) ----
    f32x4 dacc[8];
#pragma unroll
    for (int n = 0; n < 8; ++n) { dacc[n][0] = 0.f; dacc[n][1] = 0.f; dacc[n][2] = 0.f; dacc[n][3] = 0.f; }
#pragma unroll
    for (int n = 0; n < 8; ++n) {
#pragma unroll
      for (int ks = 0; ks < 4; ++ks) {
        const short8 b8 = __builtin_bit_cast(short8, *(const u32x4v*)(&Bp[(ks * 512 + n * 64 + lane) * 4]));
        dacc[n] = __builtin_amdgcn_mfma_f32_16x16x32_bf16(a8[ks], b8, dacc[n], 0, 0, 0);
      }
    }

    // ---- scale rows, store (C/D: col=l15, row=lg*4+reg — round-2 proven) ----
#pragma unroll
    for (int r = 0; r < 4; ++r) {
      const int row = vbase + lg * 4 + r;
      const float sc = out_norm[row] * out_x0[row];
      float* op = out + (size_t)row * 128 + l15;
#pragma unroll
      for (int n = 0; n < 8; ++n) op[n * 16] = sc * dacc[n][r];
    }
  }
}

extern "C" void kernel_launch(void* const* d_in, const int* in_sizes, int n_in,
                              void* d_out, int out_size, void* d_ws, size_t ws_size,
                              hipStream_t stream) {
  const float* x  = (const float*)d_in[0];
  const float* Pm = (const float*)d_in[1];
  float* out = (float*)d_out;
  // A: 262144 vec / (8 waves * 4 passes * 8 vec) = 1024 blocks, exact cover.
  hipLaunchKernelGGL(rabitq_quant, dim3(1024), dim3(512), 0, stream, x, Pm, out);
  // B: 262144 vec / (4 waves * 4 passes * 16 vec) = 1024 blocks, exact cover.
  hipLaunchKernelGGL(rabitq_dequant, dim3(1024), dim3(256), 0, stream, Pm, out);
}